// Round 10
// baseline (250.098 us; speedup 1.0000x reference)
//
#include <hip/hip_runtime.h>
#include <hip/hip_cooperative_groups.h>

namespace cg = cooperative_groups;

#define LEAK 0.2f

static __device__ __forceinline__ float leaky(float e) { return e > 0.f ? e : LEAK * e; }

// bf16 helpers (RNE pack, cheap unpack)
static __device__ __forceinline__ unsigned f2bf(float f) {
    union { float f; unsigned u; } v; v.f = f;
    return (v.u + 0x7FFFu + ((v.u >> 16) & 1u)) >> 16;
}
static __device__ __forceinline__ float bflo(unsigned u) {
    union { unsigned x; float f; } v; v.x = u << 16; return v.f;
}
static __device__ __forceinline__ float bfhi(unsigned u) {
    union { unsigned x; float f; } v; v.x = u & 0xFFFF0000u; return v.f;
}

using bf16x8 = __attribute__((ext_vector_type(8))) short;
using f32x4 = __attribute__((ext_vector_type(4))) float;

// ---------------- cooperative CSR builder ----------------
// One kernel, 5 phases split by grid.sync():
//  A: zero counts; detect int64-vs-int32; transpose W1/W2 -> bf16 [F][K]
//  B: rank pass — r=atomicAdd(counts[d]); store packed (r<<16|d) + src, int4-coalesced
//     (pack valid: N <= 65536 and max degree < 32768; here N=50000, deg~Poisson(12.8))
//  C: per-chunk inclusive scan of counts -> rowptr[g+1] (block-local), bsums[chunk]
//  D: every block re-scans the <=256 bsums in LDS, adds prefix to its chunks
//  E: place — colv[rowptr[d]+r] = s, no atomics, 4 independent scatters/thread
// 256 blocks x 256 threads: co-residency guaranteed (1 block/CU floor).
__global__ __launch_bounds__(256) void k_csr(const int* __restrict__ ei, int E, int N, int nchk,
                                             int* __restrict__ flag, int* __restrict__ counts,
                                             int* __restrict__ bsums, int* __restrict__ rowptr,
                                             int* __restrict__ rankd, int* __restrict__ srcv,
                                             int* __restrict__ colv,
                                             const float* __restrict__ W1,
                                             unsigned short* __restrict__ Wt1,
                                             const float* __restrict__ W2,
                                             unsigned short* __restrict__ Wt2) {
    cg::grid_group grid = cg::this_grid();
    __shared__ int s[256];
    int t = threadIdx.x, bid = blockIdx.x;
    int G = gridDim.x;
    int gid = bid * 256 + t, GT = G * 256;

    // ---- phase A ----
    for (int i = gid; i < N; i += GT) counts[i] = 0;
    if (bid == 0) {
        if (t < 64) {
            int bad = 0;
            for (int i = 1 + 2 * t; i < nchk; i += 128) bad |= (ei[i] != 0);
            unsigned long long ab = __ballot(bad != 0);
            if (t == 0) *flag = (ab == 0ULL) ? 1 : 0;  // 1 => int64 layout
        }
    } else if (bid <= 4) {                 // W1: 128x128, quarter covers 32 k
        int q = bid - 1;
        int c = t & 127, ksub = t >> 7;
        int k0 = q * 32 + ksub * 16;
        union { unsigned short us[16]; uint4 v[2]; } u;
#pragma unroll
        for (int j = 0; j < 16; ++j) u.us[j] = (unsigned short)f2bf(W1[(size_t)(k0 + j) * 128 + c]);
        uint4* dst = (uint4*)(Wt1 + (size_t)c * 128 + k0);
        dst[0] = u.v[0];
        dst[1] = u.v[1];
    } else if (bid <= 6) {                 // W2: 128x64, half covers 64 k
        int q = bid - 5;
        int c = t & 63, ksub = t >> 6;
        int k0 = q * 64 + ksub * 16;
        union { unsigned short us[16]; uint4 v[2]; } u;
#pragma unroll
        for (int j = 0; j < 16; ++j) u.us[j] = (unsigned short)f2bf(W2[(size_t)(k0 + j) * 64 + c]);
        uint4* dst = (uint4*)(Wt2 + (size_t)c * 128 + k0);
        dst[0] = u.v[0];
        dst[1] = u.v[1];
    }
    grid.sync();

    // ---- phase B: rank ----
    int is64 = *(volatile int*)flag;
    for (long long base = (long long)gid * 4; base < E; base += (long long)GT * 4) {
        if (base + 3 < E) {
            int s0, s1, s2, s3, d0, d1, d2, d3;
            if (is64) {
                const uint4* ps = (const uint4*)(ei + 2 * base);
                uint4 a = ps[0], b = ps[1];
                const uint4* pd = (const uint4*)(ei + 2 * ((long long)E + base));
                uint4 c4 = pd[0], e4 = pd[1];
                s0 = a.x; s1 = a.z; s2 = b.x; s3 = b.z;
                d0 = c4.x; d1 = c4.z; d2 = e4.x; d3 = e4.z;
            } else {
                int4 a = *(const int4*)(ei + base);
                int4 b = *(const int4*)(ei + (long long)E + base);
                s0 = a.x; s1 = a.y; s2 = a.z; s3 = a.w;
                d0 = b.x; d1 = b.y; d2 = b.z; d3 = b.w;
            }
            int r0 = atomicAdd(&counts[d0], 1);
            int r1 = atomicAdd(&counts[d1], 1);
            int r2 = atomicAdd(&counts[d2], 1);
            int r3 = atomicAdd(&counts[d3], 1);
            *(int4*)(rankd + base) = make_int4((r0 << 16) | d0, (r1 << 16) | d1,
                                               (r2 << 16) | d2, (r3 << 16) | d3);
            *(int4*)(srcv + base) = make_int4(s0, s1, s2, s3);
        } else {
            for (int j = 0; j < 4 && base + j < E; ++j) {
                long long e = base + j;
                int ss = is64 ? ei[2 * e] : ei[e];
                int dd = is64 ? ei[2 * ((long long)E + e)] : ei[(long long)E + e];
                int r = atomicAdd(&counts[dd], 1);
                rankd[e] = (r << 16) | dd;
                srcv[e] = ss;
            }
        }
    }
    grid.sync();

    // ---- phase C: per-chunk inclusive scans ----
    int NBc = (N + 255) / 256;   // must be <= 256 (N <= 65536)
    for (int c = bid; c < NBc; c += G) {
        int g = c * 256 + t;
        int v = (g < N) ? counts[g] : 0;
        s[t] = v;
        __syncthreads();
        for (int off = 1; off < 256; off <<= 1) {
            int add = (t >= off) ? s[t - off] : 0;
            __syncthreads();
            s[t] += add;
            __syncthreads();
        }
        if (g < N) rowptr[g + 1] = s[t];
        if (t == 255) bsums[c] = s[255];
        __syncthreads();
    }
    grid.sync();

    // ---- phase D: every block scans bsums, adds prefix to its chunks ----
    {
        int v = (t < NBc) ? bsums[t] : 0;
        s[t] = v;
        __syncthreads();
        for (int off = 1; off < 256; off <<= 1) {
            int add = (t >= off) ? s[t - off] : 0;
            __syncthreads();
            s[t] += add;
            __syncthreads();
        }
        for (int c = bid; c < NBc; c += G) {
            int pre = (c == 0) ? 0 : s[c - 1];
            int g = c * 256 + t;
            if (g < N) rowptr[g + 1] += pre;
        }
        if (gid == 0) rowptr[0] = 0;
    }
    grid.sync();

    // ---- phase E: place ----
    for (long long base = (long long)gid * 4; base < E; base += (long long)GT * 4) {
        if (base + 3 < E) {
            int4 rd = *(const int4*)(rankd + base);
            int4 sv = *(const int4*)(srcv + base);
            int p0 = rowptr[rd.x & 0xFFFF] + (rd.x >> 16);
            int p1 = rowptr[rd.y & 0xFFFF] + (rd.y >> 16);
            int p2 = rowptr[rd.z & 0xFFFF] + (rd.z >> 16);
            int p3 = rowptr[rd.w & 0xFFFF] + (rd.w >> 16);
            colv[p0] = sv.x;
            colv[p1] = sv.y;
            colv[p2] = sv.z;
            colv[p3] = sv.w;
        } else {
            for (int j = 0; j < 4 && base + j < E; ++j) {
                long long e = base + j;
                int rd = rankd[e];
                colv[rowptr[rd & 0xFFFF] + (rd >> 16)] = srcv[e];
            }
        }
    }
}

// ---------------- MFMA GEMM + fused alpha ----------------
template <int F, bool AF32>
__global__ __launch_bounds__(256) void k_gemm_mfma(const void* __restrict__ Xv,
                                                   const unsigned short* __restrict__ Wt,
                                                   const float* __restrict__ asrc,
                                                   const float* __restrict__ adst,
                                                   unsigned short* __restrict__ Hb,
                                                   float* __restrict__ out_s,
                                                   float* __restrict__ out_d, int n) {
    constexpr int K = 128;
    constexpr int KP = K + 8;       // padded row length (shorts)
    constexpr int NT = F / 16;      // 16-col tiles per wave stripe
    __shared__ unsigned short wsT[F * KP];
    int t = threadIdx.x;
    int w = t >> 6, lane = t & 63;
    int lrow = lane & 15, kg = lane >> 4;  // kg in 0..3
    long long row0 = (long long)blockIdx.x * 64;

    // stage Wt -> LDS (linear uint4 writes into padded rows)
#pragma unroll
    for (int i = t; i < F * (K / 8); i += 256) {
        int c = i / (K / 8), j8 = i % (K / 8);
        uint4 v = ((const uint4*)(Wt + (size_t)c * K))[j8];
        *(uint4*)&wsT[c * KP + 8 * j8] = v;
    }
    __syncthreads();

    long long grow = row0 + w * 16 + lrow;
    bool rowok = grow < n;

    f32x4 acc[NT];
#pragma unroll
    for (int i = 0; i < NT; ++i) acc[i] = (f32x4){0.f, 0.f, 0.f, 0.f};

#pragma unroll
    for (int ks = 0; ks < K / 32; ++ks) {
        bf16x8 af;
        if constexpr (AF32) {
            const float* Xp = (const float*)Xv + grow * K + ks * 32 + kg * 8;
            float4 x0 = make_float4(0.f, 0.f, 0.f, 0.f), x1 = x0;
            if (rowok) {
                x0 = ((const float4*)Xp)[0];
                x1 = ((const float4*)Xp)[1];
            }
            af = (bf16x8){(short)f2bf(x0.x), (short)f2bf(x0.y), (short)f2bf(x0.z), (short)f2bf(x0.w),
                          (short)f2bf(x1.x), (short)f2bf(x1.y), (short)f2bf(x1.z), (short)f2bf(x1.w)};
        } else {
            uint4 u = make_uint4(0, 0, 0, 0);
            if (rowok) {
                const unsigned short* Xp = (const unsigned short*)Xv + grow * K + ks * 32 + kg * 8;
                u = *(const uint4*)Xp;
            }
            af = *(bf16x8*)&u;
        }
#pragma unroll
        for (int nt = 0; nt < NT; ++nt) {
            const unsigned short* bp = &wsT[(nt * 16 + lrow) * KP + ks * 32 + kg * 8];
            uint4 ub = *(const uint4*)bp;
            bf16x8 bf = *(bf16x8*)&ub;
            acc[nt] = __builtin_amdgcn_mfma_f32_16x16x32_bf16(af, bf, acc[nt], 0, 0, 0);
        }
    }

    // fused alpha: per-row dots from f32 acc
    {
        float ps[4] = {0.f, 0.f, 0.f, 0.f}, pd[4] = {0.f, 0.f, 0.f, 0.f};
#pragma unroll
        for (int nt = 0; nt < NT; ++nt) {
            float asv = asrc[nt * 16 + lrow];
            float adv = adst[nt * 16 + lrow];
#pragma unroll
            for (int i = 0; i < 4; ++i) {
                ps[i] = fmaf(acc[nt][i], asv, ps[i]);
                pd[i] = fmaf(acc[nt][i], adv, pd[i]);
            }
        }
#pragma unroll
        for (int off = 1; off < 16; off <<= 1) {
#pragma unroll
            for (int i = 0; i < 4; ++i) {
                ps[i] += __shfl_xor(ps[i], off);
                pd[i] += __shfl_xor(pd[i], off);
            }
        }
        if (lrow == 0) {
#pragma unroll
            for (int i = 0; i < 4; ++i) {
                long long r = row0 + w * 16 + kg * 4 + i;
                if (r < n) {
                    out_s[r] = ps[i];
                    out_d[r] = pd[i];
                }
            }
        }
    }

    // epilogue: D col=lane&15, row=(lane>>4)*4+reg -> bf16 scalar stores
    int r0 = w * 16 + kg * 4;
#pragma unroll
    for (int nt = 0; nt < NT; ++nt) {
        int c = nt * 16 + lrow;
#pragma unroll
        for (int i = 0; i < 4; ++i) {
            long long r = row0 + r0 + i;
            if (r < n) Hb[r * F + c] = (unsigned short)f2bf(acc[nt][i]);
        }
    }
}

// ---------------- fused segment softmax + aggregation (wave per dst node) ----------------
template <int F, bool RELU, bool OB>
__global__ __launch_bounds__(256) void k_agg(const int* __restrict__ rowptr,
                                             const int* __restrict__ colv,
                                             const float* __restrict__ as_,
                                             const float* __restrict__ ad_,
                                             const unsigned* __restrict__ Hu,
                                             const float* __restrict__ bias,
                                             void* __restrict__ OUT, int n) {
    constexpr int FG8 = F / 8;       // uint4 slots per row (16 or 8)
    constexpr int GRP = 64 / FG8;    // edge-groups per wave (4 or 8)
    int node = blockIdx.x * 4 + (threadIdx.x >> 6);
    int lane = threadIdx.x & 63;
    if (node >= n) return;
    int rs = rowptr[node], re = rowptr[node + 1];
    int deg = re - rs;
    float adi = ad_[node];
    float e_self = leaky(as_[node] + adi);

    int scol = node;
    float e_l = -3.0e38f;
    if (lane < deg) {
        scol = colv[rs + lane];
        e_l = leaky(as_[scol] + adi);
    }
    float m = fmaxf(e_l, e_self);
    for (int base = 64; base < deg; base += 64) {  // rare: deg > 64
        if (base + lane < deg) m = fmaxf(m, leaky(as_[colv[rs + base + lane]] + adi));
    }
#pragma unroll
    for (int off = 32; off; off >>= 1) m = fmaxf(m, __shfl_xor(m, off));

    float p_l = (lane < deg) ? __expf(e_l - m) : 0.f;
    float ssum = p_l;
    for (int base = 64; base < deg; base += 64) {
        if (base + lane < deg) ssum += __expf(leaky(as_[colv[rs + base + lane]] + adi) - m);
    }
#pragma unroll
    for (int off = 32; off; off >>= 1) ssum += __shfl_xor(ssum, off);
    float pself = __expf(e_self - m);
    ssum += pself;
    float inv = 1.f / ssum;
    float w_l = p_l * inv;     // this lane's edge weight (first 64 edges)
    float wself = pself * inv;

    // ---- gather (bf16 rows as uint4 = 8 features) ----
    int grp = lane / FG8;      // which edge within a load step
    int fg = lane % FG8;       // which uint4 of the row
    const uint4* __restrict__ H16 = (const uint4*)Hu;
    float a0, a1, a2, a3, a4, a5, a6, a7;
    {
        uint4 hv = H16[(size_t)node * FG8 + fg];
        float ws0 = (grp == 0) ? wself : 0.f;
        a0 = ws0 * bflo(hv.x); a1 = ws0 * bfhi(hv.x);
        a2 = ws0 * bflo(hv.y); a3 = ws0 * bfhi(hv.y);
        a4 = ws0 * bflo(hv.z); a5 = ws0 * bfhi(hv.z);
        a6 = ws0 * bflo(hv.w); a7 = ws0 * bfhi(hv.w);
    }

    int cnt = deg < 64 ? deg : 64;
    constexpr int STEP = 4 * GRP;              // edges per unrolled iter (4 loads)
    int cntr = (cnt + STEP - 1) / STEP * STEP; // cnt rounded up (<= 64)
#pragma unroll 1
    for (int i = 0; i < cntr; i += STEP) {
        int i0 = i + grp, i1 = i + GRP + grp, i2 = i + 2 * GRP + grp, i3 = i + 3 * GRP + grp;
        int s0 = __shfl(scol, i0), s1 = __shfl(scol, i1);
        int s2 = __shfl(scol, i2), s3 = __shfl(scol, i3);
        float w0 = __shfl(w_l, i0), w1 = __shfl(w_l, i1);
        float w2 = __shfl(w_l, i2), w3 = __shfl(w_l, i3);
        uint4 g0 = H16[(size_t)s0 * FG8 + fg];
        uint4 g1 = H16[(size_t)s1 * FG8 + fg];
        uint4 g2 = H16[(size_t)s2 * FG8 + fg];
        uint4 g3 = H16[(size_t)s3 * FG8 + fg];
        a0 = fmaf(w0, bflo(g0.x), a0); a1 = fmaf(w0, bfhi(g0.x), a1);
        a2 = fmaf(w0, bflo(g0.y), a2); a3 = fmaf(w0, bfhi(g0.y), a3);
        a4 = fmaf(w0, bflo(g0.z), a4); a5 = fmaf(w0, bfhi(g0.z), a5);
        a6 = fmaf(w0, bflo(g0.w), a6); a7 = fmaf(w0, bfhi(g0.w), a7);
        a0 = fmaf(w1, bflo(g1.x), a0); a1 = fmaf(w1, bfhi(g1.x), a1);
        a2 = fmaf(w1, bflo(g1.y), a2); a3 = fmaf(w1, bfhi(g1.y), a3);
        a4 = fmaf(w1, bflo(g1.z), a4); a5 = fmaf(w1, bfhi(g1.z), a5);
        a6 = fmaf(w1, bflo(g1.w), a6); a7 = fmaf(w1, bfhi(g1.w), a7);
        a0 = fmaf(w2, bflo(g2.x), a0); a1 = fmaf(w2, bfhi(g2.x), a1);
        a2 = fmaf(w2, bflo(g2.y), a2); a3 = fmaf(w2, bfhi(g2.y), a3);
        a4 = fmaf(w2, bflo(g2.z), a4); a5 = fmaf(w2, bfhi(g2.z), a5);
        a6 = fmaf(w2, bflo(g2.w), a6); a7 = fmaf(w2, bfhi(g2.w), a7);
        a0 = fmaf(w3, bflo(g3.x), a0); a1 = fmaf(w3, bfhi(g3.x), a1);
        a2 = fmaf(w3, bflo(g3.y), a2); a3 = fmaf(w3, bfhi(g3.y), a3);
        a4 = fmaf(w3, bflo(g3.z), a4); a5 = fmaf(w3, bfhi(g3.z), a5);
        a6 = fmaf(w3, bflo(g3.w), a6); a7 = fmaf(w3, bfhi(g3.w), a7);
    }
    for (int j = rs + 64; j < re; ++j) {  // rare: deg > 64
        int s = colv[j];
        float w = __expf(leaky(as_[s] + adi) - m) * inv;
        float we = (grp == 0) ? w : 0.f;
        uint4 g = H16[(size_t)s * FG8 + fg];
        a0 = fmaf(we, bflo(g.x), a0); a1 = fmaf(we, bfhi(g.x), a1);
        a2 = fmaf(we, bflo(g.y), a2); a3 = fmaf(we, bfhi(g.y), a3);
        a4 = fmaf(we, bflo(g.z), a4); a5 = fmaf(we, bfhi(g.z), a5);
        a6 = fmaf(we, bflo(g.w), a6); a7 = fmaf(we, bfhi(g.w), a7);
    }
    // combine edge-groups (commutative float adds -> identical in all lanes)
#pragma unroll
    for (int off = FG8; off < 64; off <<= 1) {
        a0 += __shfl_xor(a0, off); a1 += __shfl_xor(a1, off);
        a2 += __shfl_xor(a2, off); a3 += __shfl_xor(a3, off);
        a4 += __shfl_xor(a4, off); a5 += __shfl_xor(a5, off);
        a6 += __shfl_xor(a6, off); a7 += __shfl_xor(a7, off);
    }
    if (grp == 0) {
        const float4* b4 = (const float4*)bias;
        float4 bv0 = b4[fg * 2], bv1 = b4[fg * 2 + 1];
        a0 += bv0.x; a1 += bv0.y; a2 += bv0.z; a3 += bv0.w;
        a4 += bv1.x; a5 += bv1.y; a6 += bv1.z; a7 += bv1.w;
        if (RELU) {
            a0 = fmaxf(a0, 0.f); a1 = fmaxf(a1, 0.f);
            a2 = fmaxf(a2, 0.f); a3 = fmaxf(a3, 0.f);
            a4 = fmaxf(a4, 0.f); a5 = fmaxf(a5, 0.f);
            a6 = fmaxf(a6, 0.f); a7 = fmaxf(a7, 0.f);
        }
        if (OB) {
            uint4 p;
            p.x = f2bf(a0) | (f2bf(a1) << 16);
            p.y = f2bf(a2) | (f2bf(a3) << 16);
            p.z = f2bf(a4) | (f2bf(a5) << 16);
            p.w = f2bf(a6) | (f2bf(a7) << 16);
            ((uint4*)OUT)[(size_t)node * FG8 + fg] = p;
        } else {
            float4* o4 = (float4*)((float*)OUT + (size_t)node * F + fg * 8);
            o4[0] = make_float4(a0, a1, a2, a3);
            o4[1] = make_float4(a4, a5, a6, a7);
        }
    }
}

// ---------------- host launch ----------------
extern "C" void kernel_launch(void* const* d_in, const int* in_sizes, int n_in,
                              void* d_out, int out_size, void* d_ws, size_t ws_size,
                              hipStream_t stream) {
    const float* x   = (const float*)d_in[0];
    const int*   ei  = (const int*)d_in[1];
    const float* W1  = (const float*)d_in[2];
    const float* a1s = (const float*)d_in[3];
    const float* a1d = (const float*)d_in[4];
    const float* b1  = (const float*)d_in[5];
    const float* W2  = (const float*)d_in[6];
    const float* a2s = (const float*)d_in[7];
    const float* a2d = (const float*)d_in[8];
    const float* b2  = (const float*)d_in[9];
    float* out = (float*)d_out;

    int N = in_sizes[0] / 128;   // 50000
    int E = in_sizes[1] / 2;     // 640000

    // workspace carve-up
    size_t off = 0;
    auto alloc = [&](size_t bytes) -> void* {
        off = (off + 255) & ~(size_t)255;
        void* p = (char*)d_ws + off;
        off += bytes;
        return p;
    };
    unsigned short* h = (unsigned short*)alloc((size_t)N * 128 * 2);      // bf16 h1 / h2
    unsigned short* out1b = (unsigned short*)alloc((size_t)N * 128 * 2);  // bf16 out1
    unsigned short* Wt1 = (unsigned short*)alloc(128 * 128 * 2);
    unsigned short* Wt2 = (unsigned short*)alloc(64 * 128 * 2);
    float* as_    = (float*)alloc((size_t)N * 4);
    float* ad_    = (float*)alloc((size_t)N * 4);
    int* counts   = (int*)alloc((size_t)N * 4);
    int* rowptr   = (int*)alloc((size_t)(N + 1) * 4);
    int* bsums    = (int*)alloc(1024);
    int* colv     = (int*)alloc((size_t)E * 4);
    int* rankd    = (int*)alloc((size_t)E * 4);
    int* srcv     = (int*)alloc((size_t)E * 4);
    int* flag     = (int*)alloc(256);

    int blocksN4 = (N + 3) / 4;
    int rowTiles = (N + 63) / 64;
    int nchk = 2 * E < 512 ? 2 * E : 512;

    // cooperative CSR build (1 launch replaces prep/rank/scan1/scan2/scan3/place)
    {
        void* args[] = {(void*)&ei, (void*)&E, (void*)&N, (void*)&nchk,
                        (void*)&flag, (void*)&counts, (void*)&bsums, (void*)&rowptr,
                        (void*)&rankd, (void*)&srcv, (void*)&colv,
                        (void*)&W1, (void*)&Wt1, (void*)&W2, (void*)&Wt2};
        hipLaunchCooperativeKernel((void*)k_csr, dim3(256), dim3(256), args, 0, stream);
    }

    // layer 1: Fh = 128 (A = x f32, converted in-register); alpha fused
    k_gemm_mfma<128, true><<<rowTiles, 256, 0, stream>>>(x, Wt1, a1s, a1d, h, as_, ad_, N);
    k_agg<128, true, true><<<blocksN4, 256, 0, stream>>>(rowptr, colv, as_, ad_,
                                                         (const unsigned*)h, b1, out1b, N);

    // layer 2: Fout = 64 (A = out1b bf16); alpha fused
    k_gemm_mfma<64, false><<<rowTiles, 256, 0, stream>>>(out1b, Wt2, a2s, a2d, h, as_, ad_, N);
    k_agg<64, false, false><<<blocksN4, 256, 0, stream>>>(rowptr, colv, as_, ad_,
                                                          (const unsigned*)h, b2, out, N);
}

// Round 11
// 135.445 us; speedup vs baseline: 1.8465x; 1.8465x over previous
//
#include <hip/hip_runtime.h>

#define LEAK 0.2f

static __device__ __forceinline__ float leaky(float e) { return e > 0.f ? e : LEAK * e; }

// bf16 helpers (RNE pack, cheap unpack)
static __device__ __forceinline__ unsigned f2bf(float f) {
    union { float f; unsigned u; } v; v.f = f;
    return (v.u + 0x7FFFu + ((v.u >> 16) & 1u)) >> 16;
}
static __device__ __forceinline__ float bflo(unsigned u) {
    union { unsigned x; float f; } v; v.x = u << 16; return v.f;
}
static __device__ __forceinline__ float bfhi(unsigned u) {
    union { unsigned x; float f; } v; v.x = u & 0xFFFF0000u; return v.f;
}

using bf16x8 = __attribute__((ext_vector_type(8))) short;
using f32x4 = __attribute__((ext_vector_type(4))) float;

// ---------------- prep: zero counts + detect edge dtype + pre-transpose W1/W2 ----------------
__global__ __launch_bounds__(256) void k_prep(int* __restrict__ counts, int n,
                                              const int* __restrict__ ei, int nwords_check,
                                              int* __restrict__ flag,
                                              const float* __restrict__ W1,
                                              unsigned short* __restrict__ Wt1,
                                              const float* __restrict__ W2,
                                              unsigned short* __restrict__ Wt2, int NB) {
    int bid = blockIdx.x;
    int t = threadIdx.x;
    if (bid == 0) {
        if (t < 64) {
            int bad = 0;
            for (int i = 1 + 2 * t; i < nwords_check; i += 128) bad |= (ei[i] != 0);
            unsigned long long anybad = __ballot(bad != 0);
            if (t == 0) *flag = (anybad == 0ULL) ? 1 : 0;  // 1 => int64 layout
        }
        return;
    }
    if (bid <= NB) {
        int i = (bid - 1) * 256 + t;
        if (i < n) counts[i] = 0;
        return;
    }
    if (bid <= NB + 4) {                 // W1: 128x128, quarter q covers 32 k
        int q = bid - (NB + 1);
        int c = t & 127, ksub = t >> 7;  // ksub 0..1
        int k0 = q * 32 + ksub * 16;
        union { unsigned short s[16]; uint4 v[2]; } u;
#pragma unroll
        for (int j = 0; j < 16; ++j) u.s[j] = (unsigned short)f2bf(W1[(size_t)(k0 + j) * 128 + c]);
        uint4* dst = (uint4*)(Wt1 + (size_t)c * 128 + k0);
        dst[0] = u.v[0];
        dst[1] = u.v[1];
        return;
    }
    {                                    // W2: 128x64, half q covers 64 k
        int q = bid - (NB + 5);
        int c = t & 63, ksub = t >> 6;   // ksub 0..3
        int k0 = q * 64 + ksub * 16;
        union { unsigned short s[16]; uint4 v[2]; } u;
#pragma unroll
        for (int j = 0; j < 16; ++j) u.s[j] = (unsigned short)f2bf(W2[(size_t)(k0 + j) * 64 + c]);
        uint4* dst = (uint4*)(Wt2 + (size_t)c * 128 + k0);
        dst[0] = u.v[0];
        dst[1] = u.v[1];
        return;
    }
}

// ---------------- CSR rank pass: r = atomicAdd(counts[d]), packed (r<<16|d) ----------------
// pack valid: N <= 65536, max degree < 32768 (here N=50000, deg ~ Poisson(12.8)).
__global__ __launch_bounds__(256) void k_rank(const int* __restrict__ ei,
                                              const int* __restrict__ flag,
                                              int* __restrict__ counts,
                                              int* __restrict__ rankd,
                                              int* __restrict__ srcv, int E) {
    int base = (blockIdx.x * 256 + threadIdx.x) * 4;
    if (base >= E) return;
    int is64 = *flag;
    if (base + 3 < E) {
        int s0, s1, s2, s3, d0, d1, d2, d3;
        if (is64) {
            const uint4* ps = (const uint4*)(ei + 2 * (size_t)base);
            uint4 a = ps[0], b = ps[1];
            const uint4* pd = (const uint4*)(ei + 2 * ((size_t)E + base));
            uint4 c = pd[0], e4 = pd[1];
            s0 = a.x; s1 = a.z; s2 = b.x; s3 = b.z;
            d0 = c.x; d1 = c.z; d2 = e4.x; d3 = e4.z;
        } else {
            int4 a = *(const int4*)(ei + base);
            int4 b = *(const int4*)(ei + (size_t)E + base);
            s0 = a.x; s1 = a.y; s2 = a.z; s3 = a.w;
            d0 = b.x; d1 = b.y; d2 = b.z; d3 = b.w;
        }
        int r0 = atomicAdd(&counts[d0], 1);
        int r1 = atomicAdd(&counts[d1], 1);
        int r2 = atomicAdd(&counts[d2], 1);
        int r3 = atomicAdd(&counts[d3], 1);
        *(int4*)(rankd + base) = make_int4((r0 << 16) | d0, (r1 << 16) | d1,
                                           (r2 << 16) | d2, (r3 << 16) | d3);
        *(int4*)(srcv + base) = make_int4(s0, s1, s2, s3);
    } else {
        for (int j = 0; j < 4 && base + j < E; ++j) {
            int e = base + j;
            int ss = is64 ? ei[2 * (size_t)e] : ei[e];
            int dd = is64 ? ei[2 * ((size_t)E + e)] : ei[(size_t)E + e];
            int r = atomicAdd(&counts[dd], 1);
            rankd[e] = (r << 16) | dd;
            srcv[e] = ss;
        }
    }
}

__global__ void k_scan1(const int* __restrict__ counts, int* __restrict__ incl,
                        int* __restrict__ bsums, int n) {
    __shared__ int s[256];
    int t = threadIdx.x;
    int g = blockIdx.x * 256 + t;
    int v = (g < n) ? counts[g] : 0;
    s[t] = v;
    __syncthreads();
    for (int off = 1; off < 256; off <<= 1) {
        int add = (t >= off) ? s[t - off] : 0;
        __syncthreads();
        s[t] += add;
        __syncthreads();
    }
    if (g < n) incl[g] = s[t];
    if (t == 255) bsums[blockIdx.x] = s[255];
}

__global__ void k_scan2(int* __restrict__ bsums, int nb) {
    __shared__ int s[256];
    int t = threadIdx.x;
    int v = (t < nb) ? bsums[t] : 0;
    s[t] = v;
    __syncthreads();
    for (int off = 1; off < 256; off <<= 1) {
        int add = (t >= off) ? s[t - off] : 0;
        __syncthreads();
        s[t] += add;
        __syncthreads();
    }
    int excl = (t == 0) ? 0 : s[t - 1];
    if (t < nb) bsums[t] = excl;
}

__global__ void k_scan3(const int* __restrict__ incl, const int* __restrict__ bsums,
                        int* __restrict__ rowptr, int n) {
    int g = blockIdx.x * 256 + threadIdx.x;
    if (g < n) rowptr[g + 1] = incl[g] + bsums[blockIdx.x];
    if (g == 0) rowptr[0] = 0;
}

// ---------------- MFMA GEMM + fused alpha, with co-scheduled place blocks ----------------
// Blocks [0, rowTiles): GEMM Hb = A @ W + alpha dots (compute-bound, MFMA).
// Blocks [rowTiles, rowTiles+placeBlocks): CSR place colv[rowptr[d]+r]=s
// (latency-bound scatter) — co-scheduled so its stalls hide under the GEMM.
template <int F, bool AF32>
__global__ __launch_bounds__(256) void k_gemm_mfma(const void* __restrict__ Xv,
                                                   const unsigned short* __restrict__ Wt,
                                                   const float* __restrict__ asrc,
                                                   const float* __restrict__ adst,
                                                   unsigned short* __restrict__ Hb,
                                                   float* __restrict__ out_s,
                                                   float* __restrict__ out_d, int n,
                                                   int rowTiles,
                                                   const int* __restrict__ rankd,
                                                   const int* __restrict__ srcv,
                                                   const int* __restrict__ rowptr,
                                                   int* __restrict__ colv, int E) {
    constexpr int K = 128;
    constexpr int KP = K + 8;       // padded row length (shorts)
    constexpr int NT = F / 16;      // 16-col tiles per wave stripe
    __shared__ unsigned short wsT[F * KP];
    int t = threadIdx.x;

    if (blockIdx.x >= rowTiles) {   // ---- place role ----
        int base = ((blockIdx.x - rowTiles) * 256 + t) * 4;
        if (base >= E) return;
        if (base + 3 < E) {
            int4 rd = *(const int4*)(rankd + base);
            int4 sv = *(const int4*)(srcv + base);
            int p0 = rowptr[rd.x & 0xFFFF] + (rd.x >> 16);
            int p1 = rowptr[rd.y & 0xFFFF] + (rd.y >> 16);
            int p2 = rowptr[rd.z & 0xFFFF] + (rd.z >> 16);
            int p3 = rowptr[rd.w & 0xFFFF] + (rd.w >> 16);
            colv[p0] = sv.x;
            colv[p1] = sv.y;
            colv[p2] = sv.z;
            colv[p3] = sv.w;
        } else {
            for (int j = 0; j < 4 && base + j < E; ++j) {
                int e = base + j;
                int rd = rankd[e];
                colv[rowptr[rd & 0xFFFF] + (rd >> 16)] = srcv[e];
            }
        }
        return;
    }

    // ---- GEMM role ----
    int w = t >> 6, lane = t & 63;
    int lrow = lane & 15, kg = lane >> 4;  // kg in 0..3
    long long row0 = (long long)blockIdx.x * 64;

    // stage Wt -> LDS (linear uint4 writes into padded rows)
#pragma unroll
    for (int i = t; i < F * (K / 8); i += 256) {
        int c = i / (K / 8), j8 = i % (K / 8);
        uint4 v = ((const uint4*)(Wt + (size_t)c * K))[j8];
        *(uint4*)&wsT[c * KP + 8 * j8] = v;
    }
    __syncthreads();

    long long grow = row0 + w * 16 + lrow;
    bool rowok = grow < n;

    f32x4 acc[NT];
#pragma unroll
    for (int i = 0; i < NT; ++i) acc[i] = (f32x4){0.f, 0.f, 0.f, 0.f};

#pragma unroll
    for (int ks = 0; ks < K / 32; ++ks) {
        bf16x8 af;
        if constexpr (AF32) {
            const float* Xp = (const float*)Xv + grow * K + ks * 32 + kg * 8;
            float4 x0 = make_float4(0.f, 0.f, 0.f, 0.f), x1 = x0;
            if (rowok) {
                x0 = ((const float4*)Xp)[0];
                x1 = ((const float4*)Xp)[1];
            }
            af = (bf16x8){(short)f2bf(x0.x), (short)f2bf(x0.y), (short)f2bf(x0.z), (short)f2bf(x0.w),
                          (short)f2bf(x1.x), (short)f2bf(x1.y), (short)f2bf(x1.z), (short)f2bf(x1.w)};
        } else {
            uint4 u = make_uint4(0, 0, 0, 0);
            if (rowok) {
                const unsigned short* Xp = (const unsigned short*)Xv + grow * K + ks * 32 + kg * 8;
                u = *(const uint4*)Xp;
            }
            af = *(bf16x8*)&u;
        }
#pragma unroll
        for (int nt = 0; nt < NT; ++nt) {
            const unsigned short* bp = &wsT[(nt * 16 + lrow) * KP + ks * 32 + kg * 8];
            uint4 ub = *(const uint4*)bp;
            bf16x8 bf = *(bf16x8*)&ub;
            acc[nt] = __builtin_amdgcn_mfma_f32_16x16x32_bf16(af, bf, acc[nt], 0, 0, 0);
        }
    }

    // fused alpha: per-row dots from f32 acc
    {
        float ps[4] = {0.f, 0.f, 0.f, 0.f}, pd[4] = {0.f, 0.f, 0.f, 0.f};
#pragma unroll
        for (int nt = 0; nt < NT; ++nt) {
            float asv = asrc[nt * 16 + lrow];
            float adv = adst[nt * 16 + lrow];
#pragma unroll
            for (int i = 0; i < 4; ++i) {
                ps[i] = fmaf(acc[nt][i], asv, ps[i]);
                pd[i] = fmaf(acc[nt][i], adv, pd[i]);
            }
        }
#pragma unroll
        for (int off = 1; off < 16; off <<= 1) {
#pragma unroll
            for (int i = 0; i < 4; ++i) {
                ps[i] += __shfl_xor(ps[i], off);
                pd[i] += __shfl_xor(pd[i], off);
            }
        }
        if (lrow == 0) {
#pragma unroll
            for (int i = 0; i < 4; ++i) {
                long long r = row0 + w * 16 + kg * 4 + i;
                if (r < n) {
                    out_s[r] = ps[i];
                    out_d[r] = pd[i];
                }
            }
        }
    }

    // epilogue: D col=lane&15, row=(lane>>4)*4+reg -> bf16 scalar stores
    int r0 = w * 16 + kg * 4;
#pragma unroll
    for (int nt = 0; nt < NT; ++nt) {
        int c = nt * 16 + lrow;
#pragma unroll
        for (int i = 0; i < 4; ++i) {
            long long r = row0 + r0 + i;
            if (r < n) Hb[r * F + c] = (unsigned short)f2bf(acc[nt][i]);
        }
    }
}

// ---------------- fused segment softmax + aggregation (wave per dst node) ----------------
template <int F, bool RELU, bool OB>
__global__ __launch_bounds__(256) void k_agg(const int* __restrict__ rowptr,
                                             const int* __restrict__ colv,
                                             const float* __restrict__ as_,
                                             const float* __restrict__ ad_,
                                             const unsigned* __restrict__ Hu,
                                             const float* __restrict__ bias,
                                             void* __restrict__ OUT, int n) {
    constexpr int FG8 = F / 8;       // uint4 slots per row (16 or 8)
    constexpr int GRP = 64 / FG8;    // edge-groups per wave (4 or 8)
    int node = blockIdx.x * 4 + (threadIdx.x >> 6);
    int lane = threadIdx.x & 63;
    if (node >= n) return;
    int rs = rowptr[node], re = rowptr[node + 1];
    int deg = re - rs;
    float adi = ad_[node];
    float e_self = leaky(as_[node] + adi);

    int scol = node;
    float e_l = -3.0e38f;
    if (lane < deg) {
        scol = colv[rs + lane];
        e_l = leaky(as_[scol] + adi);
    }
    float m = fmaxf(e_l, e_self);
    for (int base = 64; base < deg; base += 64) {  // rare: deg > 64
        if (base + lane < deg) m = fmaxf(m, leaky(as_[colv[rs + base + lane]] + adi));
    }
#pragma unroll
    for (int off = 32; off; off >>= 1) m = fmaxf(m, __shfl_xor(m, off));

    float p_l = (lane < deg) ? __expf(e_l - m) : 0.f;
    float ssum = p_l;
    for (int base = 64; base < deg; base += 64) {
        if (base + lane < deg) ssum += __expf(leaky(as_[colv[rs + base + lane]] + adi) - m);
    }
#pragma unroll
    for (int off = 32; off; off >>= 1) ssum += __shfl_xor(ssum, off);
    float pself = __expf(e_self - m);
    ssum += pself;
    float inv = 1.f / ssum;
    float w_l = p_l * inv;     // this lane's edge weight (first 64 edges)
    float wself = pself * inv;

    // ---- gather (bf16 rows as uint4 = 8 features) ----
    int grp = lane / FG8;      // which edge within a load step
    int fg = lane % FG8;       // which uint4 of the row
    const uint4* __restrict__ H16 = (const uint4*)Hu;
    float a0, a1, a2, a3, a4, a5, a6, a7;
    {
        uint4 hv = H16[(size_t)node * FG8 + fg];
        float ws0 = (grp == 0) ? wself : 0.f;
        a0 = ws0 * bflo(hv.x); a1 = ws0 * bfhi(hv.x);
        a2 = ws0 * bflo(hv.y); a3 = ws0 * bfhi(hv.y);
        a4 = ws0 * bflo(hv.z); a5 = ws0 * bfhi(hv.z);
        a6 = ws0 * bflo(hv.w); a7 = ws0 * bfhi(hv.w);
    }

    int cnt = deg < 64 ? deg : 64;
    constexpr int STEP = 4 * GRP;              // edges per unrolled iter (4 loads)
    int cntr = (cnt + STEP - 1) / STEP * STEP; // cnt rounded up (<= 64)
#pragma unroll 1
    for (int i = 0; i < cntr; i += STEP) {
        int i0 = i + grp, i1 = i + GRP + grp, i2 = i + 2 * GRP + grp, i3 = i + 3 * GRP + grp;
        int s0 = __shfl(scol, i0), s1 = __shfl(scol, i1);
        int s2 = __shfl(scol, i2), s3 = __shfl(scol, i3);
        float w0 = __shfl(w_l, i0), w1 = __shfl(w_l, i1);
        float w2 = __shfl(w_l, i2), w3 = __shfl(w_l, i3);
        uint4 g0 = H16[(size_t)s0 * FG8 + fg];
        uint4 g1 = H16[(size_t)s1 * FG8 + fg];
        uint4 g2 = H16[(size_t)s2 * FG8 + fg];
        uint4 g3 = H16[(size_t)s3 * FG8 + fg];
        a0 = fmaf(w0, bflo(g0.x), a0); a1 = fmaf(w0, bfhi(g0.x), a1);
        a2 = fmaf(w0, bflo(g0.y), a2); a3 = fmaf(w0, bfhi(g0.y), a3);
        a4 = fmaf(w0, bflo(g0.z), a4); a5 = fmaf(w0, bfhi(g0.z), a5);
        a6 = fmaf(w0, bflo(g0.w), a6); a7 = fmaf(w0, bfhi(g0.w), a7);
        a0 = fmaf(w1, bflo(g1.x), a0); a1 = fmaf(w1, bfhi(g1.x), a1);
        a2 = fmaf(w1, bflo(g1.y), a2); a3 = fmaf(w1, bfhi(g1.y), a3);
        a4 = fmaf(w1, bflo(g1.z), a4); a5 = fmaf(w1, bfhi(g1.z), a5);
        a6 = fmaf(w1, bflo(g1.w), a6); a7 = fmaf(w1, bfhi(g1.w), a7);
        a0 = fmaf(w2, bflo(g2.x), a0); a1 = fmaf(w2, bfhi(g2.x), a1);
        a2 = fmaf(w2, bflo(g2.y), a2); a3 = fmaf(w2, bfhi(g2.y), a3);
        a4 = fmaf(w2, bflo(g2.z), a4); a5 = fmaf(w2, bfhi(g2.z), a5);
        a6 = fmaf(w2, bflo(g2.w), a6); a7 = fmaf(w2, bfhi(g2.w), a7);
        a0 = fmaf(w3, bflo(g3.x), a0); a1 = fmaf(w3, bfhi(g3.x), a1);
        a2 = fmaf(w3, bflo(g3.y), a2); a3 = fmaf(w3, bfhi(g3.y), a3);
        a4 = fmaf(w3, bflo(g3.z), a4); a5 = fmaf(w3, bfhi(g3.z), a5);
        a6 = fmaf(w3, bflo(g3.w), a6); a7 = fmaf(w3, bfhi(g3.w), a7);
    }
    for (int j = rs + 64; j < re; ++j) {  // rare: deg > 64
        int s = colv[j];
        float w = __expf(leaky(as_[s] + adi) - m) * inv;
        float we = (grp == 0) ? w : 0.f;
        uint4 g = H16[(size_t)s * FG8 + fg];
        a0 = fmaf(we, bflo(g.x), a0); a1 = fmaf(we, bfhi(g.x), a1);
        a2 = fmaf(we, bflo(g.y), a2); a3 = fmaf(we, bfhi(g.y), a3);
        a4 = fmaf(we, bflo(g.z), a4); a5 = fmaf(we, bfhi(g.z), a5);
        a6 = fmaf(we, bflo(g.w), a6); a7 = fmaf(we, bfhi(g.w), a7);
    }
    // combine edge-groups (commutative float adds -> identical in all lanes)
#pragma unroll
    for (int off = FG8; off < 64; off <<= 1) {
        a0 += __shfl_xor(a0, off); a1 += __shfl_xor(a1, off);
        a2 += __shfl_xor(a2, off); a3 += __shfl_xor(a3, off);
        a4 += __shfl_xor(a4, off); a5 += __shfl_xor(a5, off);
        a6 += __shfl_xor(a6, off); a7 += __shfl_xor(a7, off);
    }
    if (grp == 0) {
        const float4* b4 = (const float4*)bias;
        float4 bv0 = b4[fg * 2], bv1 = b4[fg * 2 + 1];
        a0 += bv0.x; a1 += bv0.y; a2 += bv0.z; a3 += bv0.w;
        a4 += bv1.x; a5 += bv1.y; a6 += bv1.z; a7 += bv1.w;
        if (RELU) {
            a0 = fmaxf(a0, 0.f); a1 = fmaxf(a1, 0.f);
            a2 = fmaxf(a2, 0.f); a3 = fmaxf(a3, 0.f);
            a4 = fmaxf(a4, 0.f); a5 = fmaxf(a5, 0.f);
            a6 = fmaxf(a6, 0.f); a7 = fmaxf(a7, 0.f);
        }
        if (OB) {
            uint4 p;
            p.x = f2bf(a0) | (f2bf(a1) << 16);
            p.y = f2bf(a2) | (f2bf(a3) << 16);
            p.z = f2bf(a4) | (f2bf(a5) << 16);
            p.w = f2bf(a6) | (f2bf(a7) << 16);
            ((uint4*)OUT)[(size_t)node * FG8 + fg] = p;
        } else {
            float4* o4 = (float4*)((float*)OUT + (size_t)node * F + fg * 8);
            o4[0] = make_float4(a0, a1, a2, a3);
            o4[1] = make_float4(a4, a5, a6, a7);
        }
    }
}

// ---------------- host launch ----------------
extern "C" void kernel_launch(void* const* d_in, const int* in_sizes, int n_in,
                              void* d_out, int out_size, void* d_ws, size_t ws_size,
                              hipStream_t stream) {
    const float* x   = (const float*)d_in[0];
    const int*   ei  = (const int*)d_in[1];
    const float* W1  = (const float*)d_in[2];
    const float* a1s = (const float*)d_in[3];
    const float* a1d = (const float*)d_in[4];
    const float* b1  = (const float*)d_in[5];
    const float* W2  = (const float*)d_in[6];
    const float* a2s = (const float*)d_in[7];
    const float* a2d = (const float*)d_in[8];
    const float* b2  = (const float*)d_in[9];
    float* out = (float*)d_out;

    int N = in_sizes[0] / 128;   // 50000
    int E = in_sizes[1] / 2;     // 640000

    // workspace carve-up
    size_t off = 0;
    auto alloc = [&](size_t bytes) -> void* {
        off = (off + 255) & ~(size_t)255;
        void* p = (char*)d_ws + off;
        off += bytes;
        return p;
    };
    unsigned short* h = (unsigned short*)alloc((size_t)N * 128 * 2);      // bf16 h1 / h2
    unsigned short* out1b = (unsigned short*)alloc((size_t)N * 128 * 2);  // bf16 out1
    unsigned short* Wt1 = (unsigned short*)alloc(128 * 128 * 2);
    unsigned short* Wt2 = (unsigned short*)alloc(64 * 128 * 2);
    float* as_    = (float*)alloc((size_t)N * 4);
    float* ad_    = (float*)alloc((size_t)N * 4);
    int* counts   = (int*)alloc((size_t)N * 4);
    int* rowptr   = (int*)alloc((size_t)(N + 1) * 4);
    int* incl     = (int*)alloc((size_t)N * 4);
    int* bsums    = (int*)alloc(1024);
    int* colv     = (int*)alloc((size_t)E * 4);
    int* rankd    = (int*)alloc((size_t)E * 4);
    int* srcv     = (int*)alloc((size_t)E * 4);
    int* flag     = (int*)alloc(256);

    int NB = (N + 255) / 256;          // <= 256 required for single-block scan2
    int blocksN4 = (N + 3) / 4;
    int rowTiles = (N + 63) / 64;
    int blocksE4 = (E + 1023) / 1024;  // 4 edges per thread

    int nchk = 2 * E < 512 ? 2 * E : 512;
    k_prep<<<NB + 7, 256, 0, stream>>>(counts, N, ei, nchk, flag, W1, Wt1, W2, Wt2, NB);
    k_rank<<<blocksE4, 256, 0, stream>>>(ei, flag, counts, rankd, srcv, E);
    k_scan1<<<NB, 256, 0, stream>>>(counts, incl, bsums, N);
    k_scan2<<<1, 256, 0, stream>>>(bsums, NB);
    k_scan3<<<NB, 256, 0, stream>>>(incl, bsums, rowptr, N);

    // layer 1 GEMM co-scheduled with CSR place (independent work, one dispatch)
    k_gemm_mfma<128, true><<<rowTiles + blocksE4, 256, 0, stream>>>(
        x, Wt1, a1s, a1d, h, as_, ad_, N, rowTiles, rankd, srcv, rowptr, colv, E);
    k_agg<128, true, true><<<blocksN4, 256, 0, stream>>>(rowptr, colv, as_, ad_,
                                                         (const unsigned*)h, b1, out1b, N);

    // layer 2: Fout = 64 (A = out1b bf16); alpha fused; no place blocks
    k_gemm_mfma<64, false><<<rowTiles, 256, 0, stream>>>(
        out1b, Wt2, a2s, a2d, h, as_, ad_, N, rowTiles, rankd, srcv, rowptr, colv, 0);
    k_agg<64, false, false><<<blocksN4, 256, 0, stream>>>(rowptr, colv, as_, ad_,
                                                          (const unsigned*)h, b2, out, N);
}